// Round 2
// baseline (732.870 us; speedup 1.0000x reference)
//
#include <hip/hip_runtime.h>

// SSIM loss, fused separable, LDS-traffic-minimized.
// B*C=48 images of 512x512 fp32. 11x11 Gaussian window, separable via
// row-sums (w1[i] = sum_j window[i][j], exact since sum(w1)==1).
//
// Round-2 structure (round-1 was LDS-issue-bound, ~8700 LDS-pipe cyc/block):
//  - NO sp/st staging: horizontal pass reads global directly (L1/L2 cached),
//    aligned float4 loads for interior tiles, guarded scalar on borders.
//  - h-pass unit = (1 row, 4 cols): pixel products computed once per pixel,
//    hb written with lane-contiguous ds_write_b128.
//  - v-pass unit = (1 col, 4 rows): 14 column values per field reused across
//    4 outputs (70 ds_read_b32 per 4 px vs 220 naive).
//  - finalize folded in via last-block-done counter (one fewer graph node).

#define WSZ   11
#define RAD   5
#define TILE  32
#define IN    42          // TILE + 2*RAD
#define BLOCK 256
#define NWAVE (BLOCK/64)

__global__ __launch_bounds__(BLOCK, 4) void ssim_fused_kernel(
    const float* __restrict__ pred,
    const float* __restrict__ target,
    const float* __restrict__ window,
    double* __restrict__ acc,
    unsigned* __restrict__ counter,
    float* __restrict__ out,
    int H, int W, double invN)
{
    __shared__ float hb[5][IN][TILE];   // h-blurred p, t, p^2, t^2, p*t
    __shared__ float w1s[WSZ];
    __shared__ float wavesum[NWAVE];

    const int t = threadIdx.x;

    // Recover separable 1D window (row sums of the 2D window).
    if (t < WSZ) {
        float s = 0.f;
        #pragma unroll
        for (int j = 0; j < WSZ; ++j) s += window[t * WSZ + j];
        w1s[t] = s;
    }

    const int tiles_x = W / TILE;
    const int tiles_per_img = tiles_x * (H / TILE);
    const int img = blockIdx.x / tiles_per_img;
    const int rem = blockIdx.x % tiles_per_img;
    const int tyi = rem / tiles_x;
    const int txi = rem % tiles_x;
    const int row0 = tyi * TILE - RAD;
    const int col0 = txi * TILE - RAD;

    const float* __restrict__ p = pred   + (size_t)img * H * W;
    const float* __restrict__ q = target + (size_t)img * H * W;

    __syncthreads();
    float w[WSZ];
    #pragma unroll
    for (int k = 0; k < WSZ; ++k) w[k] = w1s[k];

    // Interior iff every float4 the vector path touches is in-bounds:
    // cols [txi*32-8, txi*32+39], rows [tyi*32-5, tyi*32+36].
    const bool interior = (txi > 0) && (txi * TILE + 40 <= W) &&
                          (tyi > 0) && (tyi * TILE + 37 <= H);

    // ---- Horizontal pass: unit u = (row r, col-group g of 4 cols) ----
    for (int u = t; u < IN * 8; u += BLOCK) {
        const int r = u >> 3, g = u & 7;
        const int gr = row0 + r;

        float pv[14], tv[14];   // sp cols 4g .. 4g+13 (abs col col0+4g+i)
        if (interior) {
            const float4* prow = reinterpret_cast<const float4*>(p + (size_t)gr * W);
            const float4* qrow = reinterpret_cast<const float4*>(q + (size_t)gr * W);
            const int b = (txi * TILE + 4 * g - 8) >> 2;   // aligned float4 idx
            float4 P[5], Q[5];
            #pragma unroll
            for (int i = 0; i < 5; ++i) { P[i] = prow[b + i]; Q[i] = qrow[b + i]; }
            const float* pf = reinterpret_cast<const float*>(P);
            const float* qf = reinterpret_cast<const float*>(Q);
            #pragma unroll
            for (int i = 0; i < 14; ++i) { pv[i] = pf[i + 3]; tv[i] = qf[i + 3]; }
        } else {
            const int cb = col0 + 4 * g;
            const bool rok = (unsigned)gr < (unsigned)H;
            #pragma unroll
            for (int i = 0; i < 14; ++i) {
                const int gc = cb + i;
                const bool ok = rok && ((unsigned)gc < (unsigned)W);
                const size_t idx = (size_t)gr * W + gc;
                pv[i] = ok ? p[idx] : 0.f;
                tv[i] = ok ? q[idx] : 0.f;
            }
        }

        // Pixel products once per pixel (not per tap).
        float pp[14], tt[14], pt[14];
        #pragma unroll
        for (int i = 0; i < 14; ++i) {
            pp[i] = pv[i] * pv[i];
            tt[i] = tv[i] * tv[i];
            pt[i] = pv[i] * tv[i];
        }

        float o1[4], o2[4], o11[4], o22[4], o12[4];
        #pragma unroll
        for (int j = 0; j < 4; ++j) {
            float s1 = 0.f, s2 = 0.f, s11 = 0.f, s22 = 0.f, s12 = 0.f;
            #pragma unroll
            for (int k = 0; k < WSZ; ++k) {
                const float wk = w[k];
                s1  += wk * pv[j + k];
                s2  += wk * tv[j + k];
                s11 += wk * pp[j + k];
                s22 += wk * tt[j + k];
                s12 += wk * pt[j + k];
            }
            o1[j] = s1; o2[j] = s2; o11[j] = s11; o22[j] = s22; o12[j] = s12;
        }

        // Lane-contiguous b128 writes (lane addr = u*16 B): conflict-free.
        *reinterpret_cast<float4*>(&hb[0][r][4 * g]) = make_float4(o1[0], o1[1], o1[2], o1[3]);
        *reinterpret_cast<float4*>(&hb[1][r][4 * g]) = make_float4(o2[0], o2[1], o2[2], o2[3]);
        *reinterpret_cast<float4*>(&hb[2][r][4 * g]) = make_float4(o11[0], o11[1], o11[2], o11[3]);
        *reinterpret_cast<float4*>(&hb[3][r][4 * g]) = make_float4(o12[0], o12[1], o12[2], o12[3]); // pt
        *reinterpret_cast<float4*>(&hb[4][r][4 * g]) = make_float4(o22[0], o22[1], o22[2], o22[3]); // tt
    }
    __syncthreads();

    // ---- Vertical pass: unit = (1 col, 4 rows) -> 32x8 = 256 units ----
    const int c  = t & 31;
    const int rb = (t >> 5) * 4;

    float accv[5][4];
    #pragma unroll
    for (int f = 0; f < 5; ++f)
        #pragma unroll
        for (int j = 0; j < 4; ++j) accv[f][j] = 0.f;

    #pragma unroll
    for (int f = 0; f < 5; ++f) {
        float col[14];
        #pragma unroll
        for (int k = 0; k < 14; ++k) col[k] = hb[f][rb + k][c];
        #pragma unroll
        for (int j = 0; j < 4; ++j) {
            float s = 0.f;
            #pragma unroll
            for (int k = 0; k < WSZ; ++k) s += w[k] * col[j + k];
            accv[f][j] = s;
        }
    }

    const float C1  = 1e-4f;   // (0.01*1)^2
    const float C2  = 9e-4f;   // (0.03*1)^2
    const float EPS = 1e-8f;
    float local = 0.f;
    #pragma unroll
    for (int j = 0; j < 4; ++j) {
        const float m1  = accv[0][j];
        const float m2  = accv[1][j];
        const float e11 = accv[2][j];
        const float e12 = accv[3][j];
        const float e22 = accv[4][j];
        const float m1sq = m1 * m1, m2sq = m2 * m2, m12 = m1 * m2;
        const float v1 = e11 - m1sq;
        const float v2 = e22 - m2sq;
        const float cv = e12 - m12;
        const float num = (2.f * m12 + C1) * (2.f * cv + C2);
        const float den = (m1sq + m2sq + C1) * (v1 + v2 + C2) + EPS;
        local += num / den;
    }

    // Wave shuffle reduce, cross-wave via LDS, one f64 atomic per block.
    #pragma unroll
    for (int off = 32; off > 0; off >>= 1)
        local += __shfl_down(local, off, 64);
    const int lane = t & 63, wid = t >> 6;
    if (lane == 0) wavesum[wid] = local;
    __syncthreads();
    if (t == 0) {
        float s = 0.f;
        #pragma unroll
        for (int wv = 0; wv < NWAVE; ++wv) s += wavesum[wv];
        atomicAdd(acc, (double)s);          // device-scope
        __threadfence();
        const unsigned prev = atomicAdd(counter, 1u);
        if (prev == gridDim.x - 1) {        // last block finalizes
            const double total = atomicAdd(acc, 0.0);
            out[0] = (float)(1.0 - total * invN);
        }
    }
}

extern "C" void kernel_launch(void* const* d_in, const int* in_sizes, int n_in,
                              void* d_out, int out_size, void* d_ws, size_t ws_size,
                              hipStream_t stream)
{
    const float* pred   = (const float*)d_in[0];
    const float* target = (const float*)d_in[1];
    const float* window = (const float*)d_in[2];
    float*  out     = (float*)d_out;
    double* acc     = (double*)d_ws;
    unsigned* counter = (unsigned*)((char*)d_ws + sizeof(double));

    const int B = 16, C = 3, H = 512, W = 512;
    const int n_img = B * C;
    const int tiles = n_img * (H / TILE) * (W / TILE);   // 12288

    // ws is re-poisoned 0xAA before every timed launch: zero acc + counter.
    hipMemsetAsync(d_ws, 0, 16, stream);

    const double invN = 1.0 / ((double)n_img * H * W);
    ssim_fused_kernel<<<tiles, BLOCK, 0, stream>>>(
        pred, target, window, acc, counter, out, H, W, invN);
}